// Round 10
// baseline (370.038 us; speedup 1.0000x reference)
//
#include <hip/hip_runtime.h>
#include <hip/hip_bf16.h>

// GAT 2-layer; reference returns h[0] only => compute the 2-hop in-neighborhood
// slice of node 0. Round-7 post-mortem: NBLK=1024 cooperative launch was
// rejected (absmax == max|ref| => all-zero output, kernel never ran; return
// code unchecked). Revert to the PROVEN co-residency point: NBLK=512,
// __launch_bounds__(256,2) (512-block coop launch ran fine in round 3).
// Keep round-5's ILP fix: 16 outstanding loads per thread in mm1/mm2, FMA
// order bit-identical to the round-4 passing kernel.
// Phases: A scan1 | B scan2 | C mm1 | DE agg+mm2 | F final   (4 gbars)

#define NEG_SLOPE 0.2f

constexpr int INDIM = 768;
constexpr int HEADS = 4;
constexpr int HID   = 128;
constexpr int HD    = HEADS * HID;  // 512
constexpr int OUTD  = 128;

constexpr int MAXL1 = 512;    // edges into node 0 (expected ~11)
constexpr int MAXU1 = 512;    // unique 1-hop sources
constexpr int MAXL2 = 4096;   // edges into U1 (expected ~130)
constexpr int MAXU2 = 2048;   // unique 2-hop sources (expected ~130)
constexpr int CAPE  = 512;    // per-node in-edge cap in aggregation

constexpr int NBLK   = 512;   // 2 blocks/CU on 256 CUs -> co-resident (proven r3)
constexpr int NTHR   = 256;
constexpr int LEAVES = 32;
constexpr int BPL    = NBLK / LEAVES;  // 16 blocks per leaf

// ctrl[] layout (ints), cacheline-separated:
constexpr int C_NL1 = 0, C_NU1 = 1, C_NL2 = 2, C_NU2 = 3;
constexpr int B_LEAF = 16;    // 32 leaf counters: ctrl[16..47]
constexpr int B_ROOT = 64;
constexpr int B_GEN  = 80;
constexpr int B_INIT = 96;
constexpr int CTRLN  = 128;

#define POISON ((int)0xAAAAAAAA)
#define MAGIC  ((int)0x5ca1ab1e)

// Tree grid barrier: monotonic counters, one releaser per round.
// Release/acquire via __threadfence (agent-scope), far-load spin + s_sleep.
// Verified working cross-XCD in rounds 3-4 (absmax 0.0, passed).
__device__ inline void gbar(int* ctrl) {
  __syncthreads();
  if (threadIdx.x == 0) {
    int g = __hip_atomic_load(&ctrl[B_GEN], __ATOMIC_RELAXED,
                              __HIP_MEMORY_SCOPE_AGENT);
    __threadfence();  // release: make this block's phase writes visible
    int a = atomicAdd(&ctrl[B_LEAF + (blockIdx.x & (LEAVES - 1))], 1);
    bool rel = false;
    if (((a + 1) & (BPL - 1)) == 0) {        // last arrival at this leaf
      int r = atomicAdd(&ctrl[B_ROOT], 1);
      if (((r + 1) & (LEAVES - 1)) == 0) {   // last leaf-winner this round
        __threadfence();
        atomicExch(&ctrl[B_GEN], g + 1);
        rel = true;
      }
    }
    if (!rel) {
      while (__hip_atomic_load(&ctrl[B_GEN], __ATOMIC_RELAXED,
                               __HIP_MEMORY_SCOPE_AGENT) == g)
        __builtin_amdgcn_s_sleep(8);
    }
    __threadfence();  // acquire: drop stale cached values before phase reads
  }
  __syncthreads();
}

__device__ inline void insertU2(int v, int* ctrl, int* U2, int* mark2) {
  if (atomicCAS(&mark2[v], POISON, -1) == POISON) {
    int idx = atomicAdd(&ctrl[C_NU2], 1);
    if (idx < MAXU2) U2[idx] = v;
    atomicExch(&mark2[v], idx + 1);
  }
}

__device__ inline void insertU1(int v, int* ctrl, int* U1, int* mark1,
                                int* L2src, int* L2dst, int* U2, int* mark2) {
  if (atomicCAS(&mark1[v], POISON, -1) == POISON) {
    int idx = atomicAdd(&ctrl[C_NU1], 1);
    if (idx < MAXU1) U1[idx] = v;
    atomicExch(&mark1[v], idx + 1);
    // self-loop edge (v,v) for layer-1 aggregation, and v is a U2 source
    int q = atomicAdd(&ctrl[C_NL2], 1);
    if (q < MAXL2) { L2src[q] = v; L2dst[q] = v; }
    insertU2(v, ctrl, U2, mark2);
  }
}

__global__ void __launch_bounds__(NTHR, 2) k_fused(
    const float* __restrict__ x, const int* __restrict__ src,
    const int* __restrict__ dst, int N, int E,
    const float* __restrict__ W1, const float* __restrict__ a_s1,
    const float* __restrict__ a_d1, const float* __restrict__ b1,
    const float* __restrict__ W2, const float* __restrict__ a_s2,
    const float* __restrict__ a_d2, const float* __restrict__ b2,
    int* ctrl, int* L1src, int* U1, int* L2src, int* L2dst, int* U2,
    int* mark1, int* mark2,
    float* as1, float* ad1, float* h1proj, float* h2proj,
    float* as2, float* ad2, float* out)
{
  const int t   = threadIdx.x;
  const int gid = blockIdx.x * NTHR + t;
  const int gsz = gridDim.x * NTHR;

  __shared__ float xs[INDIM];        // mm1 x-row stage
  __shared__ int   es[CAPE];         // agg: src U2 slots
  __shared__ float ee[CAPE][HEADS];  // agg: edge logits/alphas
  __shared__ float hs[HD];           // fused h1 row (never hits global)
  __shared__ float part[NTHR];       // mm2 k-split partials
  __shared__ float r0[4], r1[4];
  __shared__ float mh[HEADS], dh[HEADS];
  __shared__ int ecount;

  // ---- init: block 0 zeroes counters+barrier state; others wait on flag.
  // (ws == 0xAA poison at entry per harness contract; marks stay poisoned
  //  and POISON is the "unmarked" sentinel.)
  if (blockIdx.x == 0) {
    if (t == 0) {
      for (int i = 0; i < 96; i++) ctrl[i] = 0;
      __threadfence();
      atomicExch(&ctrl[B_INIT], MAGIC);
    }
  } else if (t == 0) {
    while (__hip_atomic_load(&ctrl[B_INIT], __ATOMIC_RELAXED,
                             __HIP_MEMORY_SCOPE_AGENT) != MAGIC)
      __builtin_amdgcn_s_sleep(8);
    __threadfence();
  }
  __syncthreads();

  // ---- Phase A: edges with dst==0 -> L1 list (dups kept) + U1 dedup.
  for (int e = gid; e < E; e += gsz) {
    if (dst[e] == 0) {
      int p = atomicAdd(&ctrl[C_NL1], 1);
      if (p < MAXL1) L1src[p] = src[e];
      insertU1(src[e], ctrl, U1, mark1, L2src, L2dst, U2, mark2);
    }
  }
  if (gid == 0) {  // self loop (0,0)
    int p = atomicAdd(&ctrl[C_NL1], 1);
    if (p < MAXL1) L1src[p] = 0;
    insertU1(0, ctrl, U1, mark1, L2src, L2dst, U2, mark2);
  }
  gbar(ctrl);

  // ---- Phase B: edges into U1 -> L2 list + U2 dedup.
  for (int e = gid; e < E; e += gsz) {
    int d = dst[e];
    if (mark1[d] != POISON) {
      int p = atomicAdd(&ctrl[C_NL2], 1);
      if (p < MAXL2) { L2src[p] = src[e]; L2dst[p] = d; }
      insertU2(src[e], ctrl, U2, mark2);
    }
  }
  gbar(ctrl);

  // ---- Phase C: h1proj[u] = x[u] @ W1 + attn logits. Task = (u, head-pair).
  // 16 loads in flight per thread; FMA order identical to the old 4-acc loop.
  {
    int nU2v = ctrl[C_NU2]; if (nU2v > MAXU2) nU2v = MAXU2;
    int ntask = nU2v * 2;
    for (int wk = blockIdx.x; wk < ntask; wk += gridDim.x) {
      int u = wk >> 1, hh = wk & 1;
      int node = U2[u];
      __syncthreads();
      for (int k = t; k < INDIM; k += NTHR) xs[k] = x[(size_t)node * INDIM + k];
      __syncthreads();
      int h = hh * 2 + (t >> 7), col = t & 127;
      const float* w = W1 + h * HID + col;  // W1 row-major [768,512]
      float a0 = 0.f, a1 = 0.f, a2 = 0.f, a3 = 0.f;
      for (int k = 0; k < INDIM; k += 16) {
        float wv[16];
        #pragma unroll
        for (int j = 0; j < 16; j++) wv[j] = w[(size_t)(k + j) * HD];
        #pragma unroll
        for (int j = 0; j < 16; j += 4) {   // same accumulation order as before
          a0 += xs[k + j + 0] * wv[j + 0];
          a1 += xs[k + j + 1] * wv[j + 1];
          a2 += xs[k + j + 2] * wv[j + 2];
          a3 += xs[k + j + 3] * wv[j + 3];
        }
      }
      float acc = (a0 + a1) + (a2 + a3);
      h1proj[(size_t)u * HD + h * HID + col] = acc;
      float ps = acc * a_s1[h * HID + col];
      float pd = acc * a_d1[h * HID + col];
      for (int off = 32; off > 0; off >>= 1) {
        ps += __shfl_down(ps, off);
        pd += __shfl_down(pd, off);
      }
      int wid = t >> 6, lane = t & 63;
      if (lane == 0) { r0[wid] = ps; r1[wid] = pd; }
      __syncthreads();
      if (t == 0) {  // deterministic fixed-order combine
        as1[u * HEADS + hh * 2]     = r0[0] + r0[1];
        as1[u * HEADS + hh * 2 + 1] = r0[2] + r0[3];
        ad1[u * HEADS + hh * 2]     = r1[0] + r1[1];
        ad1[u * HEADS + hh * 2 + 1] = r1[2] + r1[3];
      }
    }
  }
  gbar(ctrl);

  // ---- Phase DE (fused): per U1 node: softmax-aggregate -> h1 row in LDS,
  //      then immediately h1 @ W2 + layer-2 attn logits.
  {
    int nu1 = ctrl[C_NU1]; if (nu1 > MAXU1) nu1 = MAXU1;
    int nL2 = ctrl[C_NL2]; if (nL2 > MAXL2) nL2 = MAXL2;
    for (int wv0 = blockIdx.x; wv0 < nu1; wv0 += gridDim.x) {
      __syncthreads();
      int v = U1[wv0];
      int vslot = mark2[v] - 1;
      if (t == 0) ecount = 0;
      __syncthreads();
      for (int j = t; j < nL2; j += NTHR) {
        if (L2dst[j] == v) {
          int p = atomicAdd(&ecount, 1);
          if (p < CAPE) {
            int s2 = mark2[L2src[j]] - 1;
            es[p] = s2;
            #pragma unroll
            for (int h = 0; h < HEADS; h++) {
              float evv = as1[s2 * HEADS + h] + ad1[vslot * HEADS + h];
              ee[p][h] = evv > 0.f ? evv : NEG_SLOPE * evv;
            }
          }
        }
      }
      __syncthreads();
      int ne = min(ecount, CAPE);
      if (t < HEADS) {
        float mm = -1e30f;
        for (int j = 0; j < ne; j++) mm = fmaxf(mm, ee[j][t]);
        float s = 0.f;
        for (int j = 0; j < ne; j++) s += expf(ee[j][t] - mm);
        mh[t] = mm;
        dh[t] = s + 1e-16f;
      }
      __syncthreads();
      for (int idx = t; idx < ne * HEADS; idx += NTHR) {
        int j = idx >> 2, h = idx & 3;
        ee[j][h] = expf(ee[j][h] - mh[h]) / dh[h];
      }
      __syncthreads();
      {
        int col = t & 127, hp = t >> 7;
        for (int h = hp; h < HEADS; h += 2) {
          float acc = 0.f;
          for (int j = 0; j < ne; j++)
            acc += ee[j][h] * h1proj[(size_t)es[j] * HD + h * HID + col];
          acc += b1[h * HID + col];
          hs[h * HID + col] = fmaxf(acc, 0.f);  // +b1, ReLU; stays in LDS
        }
      }
      __syncthreads();
      // mm2 on hs: k split across two thread-halves; 16 loads in flight.
      {
        int col = t & 127, kh = t >> 7;
        const float* wp = W2 + col;       // W2 row-major [512,128]
        float a0 = 0.f, a1 = 0.f, a2 = 0.f, a3 = 0.f;
        int k0 = kh * 256;
        for (int k = k0; k < k0 + 256; k += 16) {
          float wv[16];
          #pragma unroll
          for (int j = 0; j < 16; j++) wv[j] = wp[(size_t)(k + j) * OUTD];
          #pragma unroll
          for (int j = 0; j < 16; j += 4) {  // same accumulation order
            a0 += hs[k + j + 0] * wv[j + 0];
            a1 += hs[k + j + 1] * wv[j + 1];
            a2 += hs[k + j + 2] * wv[j + 2];
            a3 += hs[k + j + 3] * wv[j + 3];
          }
        }
        part[t] = (a0 + a1) + (a2 + a3);
      }
      __syncthreads();
      if (t < 128) {
        float acc = part[t] + part[t + 128];   // fixed order
        h2proj[(size_t)wv0 * OUTD + t] = acc;
        float ps = acc * a_s2[t];
        float pd = acc * a_d2[t];
        for (int off = 32; off > 0; off >>= 1) {
          ps += __shfl_down(ps, off);
          pd += __shfl_down(pd, off);
        }
        int wid = t >> 6, lane = t & 63;
        if (lane == 0) { r0[wid] = ps; r1[wid] = pd; }
      }
      __syncthreads();
      if (t == 0) { as2[wv0] = r0[0] + r0[1]; ad2[wv0] = r1[0] + r1[1]; }
    }
  }
  gbar(ctrl);

  // ---- Phase F: layer-2 softmax + aggregate at node 0 (block 0 only)
  if (blockIdx.x == 0 && t < 128) {
    int nL1 = ctrl[C_NL1]; if (nL1 > MAXL1) nL1 = MAXL1;
    int slot0 = mark1[0] - 1;
    float ad = ad2[slot0];
    float mm = -1e30f;
    for (int j = 0; j < nL1; j++) {
      int sl = mark1[L1src[j]] - 1;
      float e = as2[sl] + ad;
      e = e > 0.f ? e : NEG_SLOPE * e;
      mm = fmaxf(mm, e);
    }
    float den = 0.f;
    for (int j = 0; j < nL1; j++) {
      int sl = mark1[L1src[j]] - 1;
      float e = as2[sl] + ad;
      e = e > 0.f ? e : NEG_SLOPE * e;
      den += expf(e - mm);
    }
    den += 1e-16f;
    float acc = 0.f;
    for (int j = 0; j < nL1; j++) {
      int sl = mark1[L1src[j]] - 1;
      float e = as2[sl] + ad;
      e = e > 0.f ? e : NEG_SLOPE * e;
      acc += (expf(e - mm) / den) * h2proj[(size_t)sl * OUTD + t];
    }
    out[t] = acc + b2[t];
  }
}

extern "C" void kernel_launch(void* const* d_in, const int* in_sizes, int n_in,
                              void* d_out, int out_size, void* d_ws, size_t ws_size,
                              hipStream_t stream) {
  const float* x    = (const float*)d_in[0];
  const int*   ei   = (const int*)d_in[1];
  const float* W1   = (const float*)d_in[2];
  const float* a_s1 = (const float*)d_in[3];
  const float* a_d1 = (const float*)d_in[4];
  const float* b1   = (const float*)d_in[5];
  const float* W2   = (const float*)d_in[6];
  const float* a_s2 = (const float*)d_in[7];
  const float* a_d2 = (const float*)d_in[8];
  const float* b2   = (const float*)d_in[9];
  float* out = (float*)d_out;

  int N = in_sizes[0] / INDIM;   // 50000
  int E = in_sizes[1] / 2;       // 500000
  const float* xp = x;
  const int* srcp = ei;
  const int* dstp = ei + E;

  // bump allocator on workspace (256B aligned)
  char* p = (char*)d_ws;
  auto alloc = [&](size_t bytes) -> void* {
    void* r = (void*)p;
    p += (bytes + 255) & ~(size_t)255;
    return r;
  };
  int* ctrl  = (int*)alloc(CTRLN * sizeof(int));
  int* L1src = (int*)alloc(MAXL1 * sizeof(int));
  int* U1    = (int*)alloc(MAXU1 * sizeof(int));
  int* L2src = (int*)alloc(MAXL2 * sizeof(int));
  int* L2dst = (int*)alloc(MAXL2 * sizeof(int));
  int* U2    = (int*)alloc(MAXU2 * sizeof(int));
  int* mark1 = (int*)alloc((size_t)N * sizeof(int));
  int* mark2 = (int*)alloc((size_t)N * sizeof(int));
  float* as1    = (float*)alloc((size_t)MAXU2 * HEADS * sizeof(float));
  float* ad1    = (float*)alloc((size_t)MAXU2 * HEADS * sizeof(float));
  float* h1proj = (float*)alloc((size_t)MAXU2 * HD * sizeof(float));
  float* h2proj = (float*)alloc((size_t)MAXU1 * OUTD * sizeof(float));
  float* as2    = (float*)alloc(MAXU1 * sizeof(float));
  float* ad2    = (float*)alloc(MAXU1 * sizeof(float));

  void* kargs[] = {
    (void*)&xp, (void*)&srcp, (void*)&dstp, (void*)&N, (void*)&E,
    (void*)&W1, (void*)&a_s1, (void*)&a_d1, (void*)&b1,
    (void*)&W2, (void*)&a_s2, (void*)&a_d2, (void*)&b2,
    (void*)&ctrl, (void*)&L1src, (void*)&U1, (void*)&L2src, (void*)&L2dst,
    (void*)&U2, (void*)&mark1, (void*)&mark2,
    (void*)&as1, (void*)&ad1, (void*)&h1proj, (void*)&h2proj,
    (void*)&as2, (void*)&ad2, (void*)&out
  };
  hipLaunchCooperativeKernel((const void*)k_fused, dim3(NBLK), dim3(NTHR),
                             kargs, 0, stream);
}

// Round 12
// 264.848 us; speedup vs baseline: 1.3972x; 1.3972x over previous
//
#include <hip/hip_runtime.h>
#include <hip/hip_bf16.h>

// GAT 2-layer; reference returns h[0] only => compute the 2-hop in-neighborhood
// slice of node 0.
// Round-10 post-mortem: the hand-rolled grid barrier costs ~25-35us EACH
// (agent-scope fence = L2 writeback+invalidate per block, cross-XCD atomic
// serialization); 4 barriers = ~120-140us of the 152us dispatch. Graph-captured
// kernel boundaries cost only ~2-4us (round-1 evidence: 9 naive kernels beat
// every fused version). So: split back into 6 small launches, no device
// barriers, POISON-sentinel marks (no N-sized init), phase math verbatim from
// the round-10 passing kernel (absmax 0.0).
// Launches: Z zero-ctrl | A scan1+U1 | B scan2+U2 | C mm1 | DE agg+mm2 | F final

#define NEG_SLOPE 0.2f

constexpr int INDIM = 768;
constexpr int HEADS = 4;
constexpr int HID   = 128;
constexpr int HD    = HEADS * HID;  // 512
constexpr int OUTD  = 128;

constexpr int MAXL1 = 512;    // edges into node 0 (expected ~11)
constexpr int MAXU1 = 512;    // unique 1-hop sources
constexpr int MAXL2 = 4096;   // edges into U1 (expected ~130)
constexpr int MAXU2 = 2048;   // unique 2-hop sources (expected ~130)
constexpr int CAPE  = 512;    // per-node in-edge cap in aggregation

constexpr int NTHR  = 256;

// ctrl[] counters:
constexpr int C_NL1 = 0, C_NU1 = 1, C_NL2 = 2, C_NU2 = 3;
constexpr int CTRLN = 16;

#define POISON ((int)0xAAAAAAAA)

__device__ inline void insertU2(int v, int* ctrl, int* U2, int* mark2) {
  if (atomicCAS(&mark2[v], POISON, -1) == POISON) {
    int idx = atomicAdd(&ctrl[C_NU2], 1);
    if (idx < MAXU2) U2[idx] = v;
    atomicExch(&mark2[v], idx + 1);
  }
}

__device__ inline void insertU1(int v, int* ctrl, int* U1, int* mark1,
                                int* L2src, int* L2dst, int* U2, int* mark2) {
  if (atomicCAS(&mark1[v], POISON, -1) == POISON) {
    int idx = atomicAdd(&ctrl[C_NU1], 1);
    if (idx < MAXU1) U1[idx] = v;
    atomicExch(&mark1[v], idx + 1);
    // self-loop edge (v,v) for layer-1 aggregation, and v is a U2 source
    int q = atomicAdd(&ctrl[C_NL2], 1);
    if (q < MAXL2) { L2src[q] = v; L2dst[q] = v; }
    insertU2(v, ctrl, U2, mark2);
  }
}

// ---- Z: zero the counters (marks stay 0xAA-poisoned = "unmarked" sentinel)
__global__ void k_zero(int* ctrl) {
  if (threadIdx.x < CTRLN) ctrl[threadIdx.x] = 0;
}

// ---- A: edges with dst==0 -> L1 list (dups kept) + U1 dedup (+self loop 0,0)
__global__ void __launch_bounds__(NTHR) k_scanA(
    const int* __restrict__ src, const int* __restrict__ dst, int E,
    int* ctrl, int* L1src, int* U1, int* mark1,
    int* L2src, int* L2dst, int* U2, int* mark2) {
  int gid = blockIdx.x * NTHR + threadIdx.x;
  int gsz = gridDim.x * NTHR;
  for (int e = gid; e < E; e += gsz) {
    if (dst[e] == 0) {
      int p = atomicAdd(&ctrl[C_NL1], 1);
      if (p < MAXL1) L1src[p] = src[e];
      insertU1(src[e], ctrl, U1, mark1, L2src, L2dst, U2, mark2);
    }
  }
  if (gid == 0) {  // self loop (0,0)
    int p = atomicAdd(&ctrl[C_NL1], 1);
    if (p < MAXL1) L1src[p] = 0;
    insertU1(0, ctrl, U1, mark1, L2src, L2dst, U2, mark2);
  }
}

// ---- B: edges into U1 -> L2 list + U2 dedup
__global__ void __launch_bounds__(NTHR) k_scanB(
    const int* __restrict__ src, const int* __restrict__ dst, int E,
    int* ctrl, const int* __restrict__ mark1,
    int* L2src, int* L2dst, int* U2, int* mark2) {
  int gid = blockIdx.x * NTHR + threadIdx.x;
  int gsz = gridDim.x * NTHR;
  for (int e = gid; e < E; e += gsz) {
    int d = dst[e];
    if (mark1[d] != POISON) {
      int p = atomicAdd(&ctrl[C_NL2], 1);
      if (p < MAXL2) { L2src[p] = src[e]; L2dst[p] = d; }
      insertU2(src[e], ctrl, U2, mark2);
    }
  }
}

// ---- C: h1proj[u] = x[u] @ W1 + attn logits. Task = (u, head-pair).
// 16 loads in flight per thread; FMA order identical to the validated loop.
__global__ void __launch_bounds__(NTHR, 2) k_mm1(
    const float* __restrict__ x, const float* __restrict__ W1,
    const float* __restrict__ a_s1, const float* __restrict__ a_d1,
    const int* __restrict__ ctrl, const int* __restrict__ U2,
    float* h1proj, float* as1, float* ad1) {
  const int t = threadIdx.x;
  __shared__ float xs[INDIM];
  __shared__ float r0[4], r1[4];
  int nU2v = ctrl[C_NU2]; if (nU2v > MAXU2) nU2v = MAXU2;
  int ntask = nU2v * 2;
  for (int wk = blockIdx.x; wk < ntask; wk += gridDim.x) {
    int u = wk >> 1, hh = wk & 1;
    int node = U2[u];
    __syncthreads();
    for (int k = t; k < INDIM; k += NTHR) xs[k] = x[(size_t)node * INDIM + k];
    __syncthreads();
    int h = hh * 2 + (t >> 7), col = t & 127;
    const float* w = W1 + h * HID + col;  // W1 row-major [768,512]
    float a0 = 0.f, a1 = 0.f, a2 = 0.f, a3 = 0.f;
    for (int k = 0; k < INDIM; k += 16) {
      float wv[16];
      #pragma unroll
      for (int j = 0; j < 16; j++) wv[j] = w[(size_t)(k + j) * HD];
      #pragma unroll
      for (int j = 0; j < 16; j += 4) {   // same accumulation order as r4/r10
        a0 += xs[k + j + 0] * wv[j + 0];
        a1 += xs[k + j + 1] * wv[j + 1];
        a2 += xs[k + j + 2] * wv[j + 2];
        a3 += xs[k + j + 3] * wv[j + 3];
      }
    }
    float acc = (a0 + a1) + (a2 + a3);
    h1proj[(size_t)u * HD + h * HID + col] = acc;
    float ps = acc * a_s1[h * HID + col];
    float pd = acc * a_d1[h * HID + col];
    for (int off = 32; off > 0; off >>= 1) {
      ps += __shfl_down(ps, off);
      pd += __shfl_down(pd, off);
    }
    int wid = t >> 6, lane = t & 63;
    if (lane == 0) { r0[wid] = ps; r1[wid] = pd; }
    __syncthreads();
    if (t == 0) {  // deterministic fixed-order combine
      as1[u * HEADS + hh * 2]     = r0[0] + r0[1];
      as1[u * HEADS + hh * 2 + 1] = r0[2] + r0[3];
      ad1[u * HEADS + hh * 2]     = r1[0] + r1[1];
      ad1[u * HEADS + hh * 2 + 1] = r1[2] + r1[3];
    }
  }
}

// ---- DE (fused): per U1 node: softmax-aggregate -> h1 row in LDS, then
//      immediately h1 @ W2 + layer-2 attn logits.
__global__ void __launch_bounds__(NTHR, 2) k_aggmm2(
    const int* __restrict__ ctrl, const int* __restrict__ U1,
    const int* __restrict__ mark2,
    const int* __restrict__ L2src, const int* __restrict__ L2dst,
    const float* __restrict__ as1, const float* __restrict__ ad1,
    const float* __restrict__ h1proj, const float* __restrict__ b1,
    const float* __restrict__ W2, const float* __restrict__ a_s2,
    const float* __restrict__ a_d2,
    float* h2proj, float* as2, float* ad2) {
  const int t = threadIdx.x;
  __shared__ int   es[CAPE];
  __shared__ float ee[CAPE][HEADS];
  __shared__ float hs[HD];
  __shared__ float part[NTHR];
  __shared__ float r0[4], r1[4];
  __shared__ float mh[HEADS], dh[HEADS];
  __shared__ int ecount;
  int nu1 = ctrl[C_NU1]; if (nu1 > MAXU1) nu1 = MAXU1;
  int nL2 = ctrl[C_NL2]; if (nL2 > MAXL2) nL2 = MAXL2;
  for (int wv0 = blockIdx.x; wv0 < nu1; wv0 += gridDim.x) {
    __syncthreads();
    int v = U1[wv0];
    int vslot = mark2[v] - 1;
    if (t == 0) ecount = 0;
    __syncthreads();
    for (int j = t; j < nL2; j += NTHR) {
      if (L2dst[j] == v) {
        int p = atomicAdd(&ecount, 1);
        if (p < CAPE) {
          int s2 = mark2[L2src[j]] - 1;
          es[p] = s2;
          #pragma unroll
          for (int h = 0; h < HEADS; h++) {
            float evv = as1[s2 * HEADS + h] + ad1[vslot * HEADS + h];
            ee[p][h] = evv > 0.f ? evv : NEG_SLOPE * evv;
          }
        }
      }
    }
    __syncthreads();
    int ne = min(ecount, CAPE);
    if (t < HEADS) {
      float mm = -1e30f;
      for (int j = 0; j < ne; j++) mm = fmaxf(mm, ee[j][t]);
      float s = 0.f;
      for (int j = 0; j < ne; j++) s += expf(ee[j][t] - mm);
      mh[t] = mm;
      dh[t] = s + 1e-16f;
    }
    __syncthreads();
    for (int idx = t; idx < ne * HEADS; idx += NTHR) {
      int j = idx >> 2, h = idx & 3;
      ee[j][h] = expf(ee[j][h] - mh[h]) / dh[h];
    }
    __syncthreads();
    {
      int col = t & 127, hp = t >> 7;
      for (int h = hp; h < HEADS; h += 2) {
        float acc = 0.f;
        for (int j = 0; j < ne; j++)
          acc += ee[j][h] * h1proj[(size_t)es[j] * HD + h * HID + col];
        acc += b1[h * HID + col];
        hs[h * HID + col] = fmaxf(acc, 0.f);  // +b1, ReLU; stays in LDS
      }
    }
    __syncthreads();
    // mm2 on hs: k split across two thread-halves; 16 loads in flight.
    {
      int col = t & 127, kh = t >> 7;
      const float* wp = W2 + col;       // W2 row-major [512,128]
      float a0 = 0.f, a1 = 0.f, a2 = 0.f, a3 = 0.f;
      int k0 = kh * 256;
      for (int k = k0; k < k0 + 256; k += 16) {
        float wv[16];
        #pragma unroll
        for (int j = 0; j < 16; j++) wv[j] = wp[(size_t)(k + j) * OUTD];
        #pragma unroll
        for (int j = 0; j < 16; j += 4) {  // same accumulation order
          a0 += hs[k + j + 0] * wv[j + 0];
          a1 += hs[k + j + 1] * wv[j + 1];
          a2 += hs[k + j + 2] * wv[j + 2];
          a3 += hs[k + j + 3] * wv[j + 3];
        }
      }
      part[t] = (a0 + a1) + (a2 + a3);
    }
    __syncthreads();
    if (t < 128) {
      float acc = part[t] + part[t + 128];   // fixed order
      h2proj[(size_t)wv0 * OUTD + t] = acc;
      float ps = acc * a_s2[t];
      float pd = acc * a_d2[t];
      for (int off = 32; off > 0; off >>= 1) {
        ps += __shfl_down(ps, off);
        pd += __shfl_down(pd, off);
      }
      int wid = t >> 6, lane = t & 63;
      if (lane == 0) { r0[wid] = ps; r1[wid] = pd; }
    }
    __syncthreads();
    if (t == 0) { as2[wv0] = r0[0] + r0[1]; ad2[wv0] = r1[0] + r1[1]; }
  }
}

// ---- F: layer-2 softmax + aggregate at node 0
__global__ void k_final(
    const int* __restrict__ ctrl, const int* __restrict__ L1src,
    const int* __restrict__ mark1,
    const float* __restrict__ as2, const float* __restrict__ ad2,
    const float* __restrict__ h2proj, const float* __restrict__ b2,
    float* __restrict__ out) {
  int t = threadIdx.x;  // 128
  int nL1 = ctrl[C_NL1]; if (nL1 > MAXL1) nL1 = MAXL1;
  int slot0 = mark1[0] - 1;
  float ad = ad2[slot0];
  float mm = -1e30f;
  for (int j = 0; j < nL1; j++) {
    int sl = mark1[L1src[j]] - 1;
    float e = as2[sl] + ad;
    e = e > 0.f ? e : NEG_SLOPE * e;
    mm = fmaxf(mm, e);
  }
  float den = 0.f;
  for (int j = 0; j < nL1; j++) {
    int sl = mark1[L1src[j]] - 1;
    float e = as2[sl] + ad;
    e = e > 0.f ? e : NEG_SLOPE * e;
    den += expf(e - mm);
  }
  den += 1e-16f;
  float acc = 0.f;
  for (int j = 0; j < nL1; j++) {
    int sl = mark1[L1src[j]] - 1;
    float e = as2[sl] + ad;
    e = e > 0.f ? e : NEG_SLOPE * e;
    acc += (expf(e - mm) / den) * h2proj[(size_t)sl * OUTD + t];
  }
  out[t] = acc + b2[t];
}

extern "C" void kernel_launch(void* const* d_in, const int* in_sizes, int n_in,
                              void* d_out, int out_size, void* d_ws, size_t ws_size,
                              hipStream_t stream) {
  const float* x    = (const float*)d_in[0];
  const int*   ei   = (const int*)d_in[1];
  const float* W1   = (const float*)d_in[2];
  const float* a_s1 = (const float*)d_in[3];
  const float* a_d1 = (const float*)d_in[4];
  const float* b1   = (const float*)d_in[5];
  const float* W2   = (const float*)d_in[6];
  const float* a_s2 = (const float*)d_in[7];
  const float* a_d2 = (const float*)d_in[8];
  const float* b2   = (const float*)d_in[9];
  float* out = (float*)d_out;

  int N = in_sizes[0] / INDIM;   // 50000
  int E = in_sizes[1] / 2;       // 500000
  const int* srcp = ei;
  const int* dstp = ei + E;
  (void)N;

  // bump allocator on workspace (256B aligned)
  char* p = (char*)d_ws;
  auto alloc = [&](size_t bytes) -> void* {
    void* r = (void*)p;
    p += (bytes + 255) & ~(size_t)255;
    return r;
  };
  int* ctrl  = (int*)alloc(CTRLN * sizeof(int));
  int* L1src = (int*)alloc(MAXL1 * sizeof(int));
  int* U1    = (int*)alloc(MAXU1 * sizeof(int));
  int* L2src = (int*)alloc(MAXL2 * sizeof(int));
  int* L2dst = (int*)alloc(MAXL2 * sizeof(int));
  int* U2    = (int*)alloc(MAXU2 * sizeof(int));
  int* mark1 = (int*)alloc((size_t)N * sizeof(int));
  int* mark2 = (int*)alloc((size_t)N * sizeof(int));
  float* as1    = (float*)alloc((size_t)MAXU2 * HEADS * sizeof(float));
  float* ad1    = (float*)alloc((size_t)MAXU2 * HEADS * sizeof(float));
  float* h1proj = (float*)alloc((size_t)MAXU2 * HD * sizeof(float));
  float* h2proj = (float*)alloc((size_t)MAXU1 * OUTD * sizeof(float));
  float* as2    = (float*)alloc(MAXU1 * sizeof(float));
  float* ad2    = (float*)alloc(MAXU1 * sizeof(float));

  k_zero<<<1, 64, 0, stream>>>(ctrl);
  k_scanA<<<512, NTHR, 0, stream>>>(srcp, dstp, E, ctrl, L1src, U1, mark1,
                                    L2src, L2dst, U2, mark2);
  k_scanB<<<512, NTHR, 0, stream>>>(srcp, dstp, E, ctrl, mark1,
                                    L2src, L2dst, U2, mark2);
  k_mm1<<<512, NTHR, 0, stream>>>(x, W1, a_s1, a_d1, ctrl, U2,
                                  h1proj, as1, ad1);
  k_aggmm2<<<64, NTHR, 0, stream>>>(ctrl, U1, mark2, L2src, L2dst, as1, ad1,
                                    h1proj, b1, W2, a_s2, a_d2,
                                    h2proj, as2, ad2);
  k_final<<<1, 128, 0, stream>>>(ctrl, L1src, mark1, as2, ad2, h2proj, b2, out);
}